// Round 2
// 522.086 us; speedup vs baseline: 1.0017x; 1.0017x over previous
//
#include <hip/hip_runtime.h>
#include <hip/hip_bf16.h>

#define EPS_BN 1e-5f

constexpr int B  = 2048, F0 = 64, K = 14;
constexpr int C1 = 64,  F1 = 32;
constexpr int C2 = 128, F2 = 16;
constexpr int C3 = 256, F3 = 8;

typedef __attribute__((ext_vector_type(8))) short bf16x8;
typedef __attribute__((ext_vector_type(4))) float f32x4;

__device__ __forceinline__ float bf2f(unsigned short u) {
    union { unsigned int i; float f; } x; x.i = ((unsigned int)u) << 16; return x.f;
}
__device__ __forceinline__ unsigned short f2bf(float f) {
    union { float f; unsigned int i; } x; x.f = f;
    unsigned int r = (x.i + 0x7fffu + ((x.i >> 16) & 1u)) >> 16;
    return (unsigned short)r;
}

// async global->LDS 16B copy. HW semantics: LDS dest = wave-uniform base +
// lane*16. Callers MUST keep all 64 lanes active and pass per-lane-consecutive
// dests. Proper addrspacecasts (no integer laundering).
__device__ __forceinline__ void gl_lds16(const void* g, void* l) {
    __builtin_amdgcn_global_load_lds(
        (const __attribute__((address_space(1))) unsigned int*)g,
        (__attribute__((address_space(3))) unsigned int*)l,
        16, 0, 0);
}

// ---- fold BN into conv1 weights (fp32, layout [c][2][9] flat) ----
// also zeroes the 16B zero-source block used by conv_mfma staging
__global__ void repack_w1(const float* __restrict__ w1, const float* __restrict__ g,
                          const float* __restrict__ bb, const float* __restrict__ m,
                          const float* __restrict__ v, float* __restrict__ w1f,
                          float* __restrict__ t1, float* __restrict__ zbuf) {
    int i = blockIdx.x * 256 + threadIdx.x;
    if (i < 4) zbuf[i] = 0.0f;
    if (i < C1) {
        float s = g[i] * rsqrtf(v[i] + EPS_BN);
        t1[i] = bb[i] - m[i] * s;
    }
    if (i < C1 * 2 * 9) {
        int c = i / 18;
        float s = g[c] * rsqrtf(v[c] + EPS_BN);
        w1f[i] = w1[i] * s;
    }
}

// ---- repack conv weights into MFMA B-fragment layout, bf16, BN-folded ----
// wp[((chunk*COUT + n)*32) + kk] = W[tap][ci][n]*s[n], chunk=tap*(CIN/32)+cc, ci=cc*32+kk
template<int CIN, int COUT>
__global__ void repack_mfma(const float* __restrict__ w, const float* __restrict__ g,
                            const float* __restrict__ bb, const float* __restrict__ m,
                            const float* __restrict__ v, unsigned short* __restrict__ wp,
                            float* __restrict__ t) {
    int idx = blockIdx.x * 256 + threadIdx.x;
    if (idx < COUT) {
        float s = g[idx] * rsqrtf(v[idx] + EPS_BN);
        t[idx] = bb[idx] - m[idx] * s;
    }
    if (idx < 9 * CIN * COUT) {
        constexpr int CCS = CIN / 32;
        int kk = idx & 31;
        int rest = idx >> 5;
        int n = rest & (COUT - 1);
        int chunk = rest / COUT;        // COUT is power of 2
        int tap = chunk / CCS;          // CCS is power of 2
        int cc  = chunk & (CCS - 1);
        int ci = cc * 32 + kk;
        float s = g[n] * rsqrtf(v[n] + EPS_BN);
        wp[idx] = f2bf(w[(n * CIN + ci) * 9 + tap] * s);
    }
}

// ---- conv1 (2->64, 3x3, stride (2,1), pad 1) + BN + ReLU, NHWC bf16 out ----
__global__ void conv1_kernel(const float* __restrict__ x, const float* __restrict__ sig,
                             const float* __restrict__ w1f, const float* __restrict__ t1,
                             unsigned short* __restrict__ h1) {
    __shared__ float xs[F0 * K], ssg[F0 * K], wsh[C1 * 19], bsh[C1];
    int b = blockIdx.x, t = threadIdx.x;
    for (int i = t; i < F0 * K; i += 256) {
        xs[i]  = x[(size_t)b * F0 * K + i];
        ssg[i] = sig[(size_t)b * F0 * K + i] * 10.0f;
    }
    for (int i = t; i < C1 * 18; i += 256) {
        int c = i / 18, r = i % 18;
        wsh[c * 19 + r] = w1f[i];
    }
    if (t < C1) bsh[t] = t1[t];
    __syncthreads();
    int c = t & 63, pg = t >> 6;
    for (int p = pg; p < F1 * K; p += 4) {
        int f = p / K, k = p % K;
        float acc = bsh[c];
        #pragma unroll
        for (int df = 0; df < 3; ++df) {
            int fi = 2 * f + df - 1;
            if (fi < 0 || fi >= F0) continue;
            #pragma unroll
            for (int dk = 0; dk < 3; ++dk) {
                int ki = k + dk - 1;
                if (ki < 0 || ki >= K) continue;
                acc = fmaf(xs[fi * K + ki],  wsh[c * 19 + df * 3 + dk], acc);
                acc = fmaf(ssg[fi * K + ki], wsh[c * 19 + 9 + df * 3 + dk], acc);
            }
        }
        h1[(((size_t)b * F1 + f) * K + k) * C1 + c] = f2bf(fmaxf(acc, 0.f));
    }
}

// ---- conv2/conv3 as MFMA GEMM, v3 ----
//  * LDS linear row stride CIN + XOR chunk-swizzle (chunk ^= p&7) applied on
//    BOTH stage-source and ds_read -> bank-conflict-free av reads (T2, rule 21).
//  * staging via global_load_lds width 16, ALL 64 LANES ALWAYS ACTIVE (HW
//    writes base+lane*16; a divergent exec mask shifts the base - the v2 bug).
//    Pad rows (p=0/15, fi=-1 tile) pull their 16B from a zeroed global block.
//    ONE barrier total, no LDS zero pass, no VGPR round trip.
//  * flat 9*CCS iteration loop with 2-deep rotated bv (weight) prefetch so L2
//    latency hides under the previous step's 16 MFMAs.
template<int CIN, int COUT, int FIN, int MINW>
__launch_bounds__(256, MINW)
__global__ void conv_mfma(const unsigned short* __restrict__ hin,
                          const unsigned short* __restrict__ wp,
                          const float* __restrict__ tb,
                          const unsigned short* __restrict__ zero16,
                          unsigned short* __restrict__ hout) {
    constexpr int G = 4;
    constexpr int CHW = CIN / 8;             // 16B chunks per row
    constexpr int LOGC = (CIN == 128) ? 4 : 3;
    constexpr int NT = COUT / 64;
    constexpr int CCS = CIN / 32;
    constexpr int NIT = 9 * CCS;             // 18 (conv2) / 36 (conv3), even
    __shared__ alignas(16) unsigned short lin[G * 3 * 16 * CIN];

    const int b = blockIdx.y;
    const int f2base = blockIdx.x * G;
    const int t = threadIdx.x;

    // async stage: LDS chunk i holds global chunk (c8 ^ (p&7)) of row (fi,kin).
    // Pad rows stage zeros from zero16. All lanes active on every call.
    {
        constexpr int TOT = G * 3 * 16 * CHW;            // multiple of 256
        #pragma unroll
        for (int i = t; i < TOT; i += 256) {
            int c8 = i & (CHW - 1);
            int row = i >> LOGC;
            int p = row & 15;
            int tile = row >> 4;
            int df = tile % 3, g = tile / 3;
            int kin = p - 1;
            int fi = 2 * (f2base + g) + df - 1;          // fi < FIN always
            bool valid = (kin >= 0) & (kin < K) & (fi >= 0);
            const unsigned short* src = valid
                ? hin + (((size_t)(b * FIN + fi)) * K + kin) * CIN + ((c8 ^ (p & 7)) << 3)
                : zero16;
            gl_lds16(src, &lin[i * 8]);
        }
    }
    __syncthreads();   // drains vmcnt (gload_lds)

    const int lane = t & 63;
    const int wave = t >> 6;
    const int m = lane & 15;                 // A row / B col / D col
    const int quad = lane >> 4;
    const int nBase = wave * (COUT / 4);

    f32x4 acc[G][NT];
    #pragma unroll
    for (int nt = 0; nt < NT; ++nt) {
        float bias = tb[nBase + nt * 16 + m];
        #pragma unroll
        for (int g = 0; g < G; ++g)
            acc[g][nt] = f32x4{bias, bias, bias, bias};
    }

    // it -> (df, dk, cc)
    auto loadA = [&](int it, bf16x8* av) {
        int df = it / (3 * CCS), dk = (it / CCS) % 3, cc = it % CCS;
        int p = m + dk; p = (p > 15) ? 15 : p;           // clamped lanes hit zero row
        int cidx = (((cc * 4 + quad) ^ (p & 7)) << 3);
        #pragma unroll
        for (int g = 0; g < G; ++g)
            av[g] = *(const bf16x8*)&lin[((g * 3 + df) * 16 + p) * CIN + cidx];
    };
    auto loadB = [&](int it, bf16x8* bv) {
        int df = it / (3 * CCS), dk = (it / CCS) % 3, cc = it % CCS;
        int chunk = (df * 3 + dk) * CCS + cc;
        #pragma unroll
        for (int nt = 0; nt < NT; ++nt)
            bv[nt] = *(const bf16x8*)(wp + (((chunk * COUT + nBase + nt * 16 + m)) << 5) + quad * 8);
    };
    auto domfma = [&](bf16x8* av, bf16x8* bv) {
        #pragma unroll
        for (int g = 0; g < G; ++g)
            #pragma unroll
            for (int nt = 0; nt < NT; ++nt)
                acc[g][nt] = __builtin_amdgcn_mfma_f32_16x16x32_bf16(av[g], bv[nt], acc[g][nt], 0, 0, 0);
    };

    bf16x8 av[G], bA[NT], bB[NT];
    loadB(0, bA);
    #pragma unroll
    for (int it = 0; it < NIT; it += 2) {
        loadB(it + 1, bB);           // prefetch for second half
        loadA(it, av);
        domfma(av, bA);
        if (it + 2 < NIT) loadB(it + 2, bA);   // prefetch next pair's first half
        loadA(it + 1, av);
        domfma(av, bB);
    }

    // epilogue: D[row=quad*4+i][col=m], ReLU, bf16 NHWC store; rows 14,15 = pad
    #pragma unroll
    for (int g = 0; g < G; ++g) {
        size_t rowbase = ((size_t)(b * (FIN / 2) + f2base + g)) * K;
        #pragma unroll
        for (int nt = 0; nt < NT; ++nt) {
            int col = nBase + nt * 16 + m;
            #pragma unroll
            for (int i = 0; i < 4; ++i) {
                int row = quad * 4 + i;
                if (row < K)
                    hout[(rowbase + row) * COUT + col] = f2bf(fmaxf(acc[g][nt][i], 0.f));
            }
        }
    }
}

// ---- conv4 (256->2, kernel (8,1)) + transpose to [B,K,2] ----
__global__ void conv4_kernel(const unsigned short* __restrict__ h3,
                             const float* __restrict__ w4, float* __restrict__ out) {
    int b = blockIdx.x;
    int t = threadIdx.x;   // 256 = C3
    float wa[8], wb[8];
    #pragma unroll
    for (int f = 0; f < 8; ++f) {
        wa[f] = w4[(0 * C3 + t) * 8 + f];
        wb[f] = w4[(1 * C3 + t) * 8 + f];
    }
    float p0[K], p1[K];
    #pragma unroll
    for (int k = 0; k < K; ++k) { p0[k] = 0.f; p1[k] = 0.f; }
    for (int f = 0; f < 8; ++f) {
        #pragma unroll
        for (int k = 0; k < K; ++k) {
            float v = bf2f(h3[((size_t)(b * F3 + f) * K + k) * C3 + t]);
            p0[k] = fmaf(v, wa[f], p0[k]);
            p1[k] = fmaf(v, wb[f], p1[k]);
        }
    }
    __shared__ float red[4][2 * K];
    int lane = t & 63, wv = t >> 6;
    #pragma unroll
    for (int k = 0; k < K; ++k) {
        float a = p0[k], c = p1[k];
        #pragma unroll
        for (int off = 32; off > 0; off >>= 1) {
            a += __shfl_down(a, off, 64);
            c += __shfl_down(c, off, 64);
        }
        if (lane == 0) { red[wv][k * 2 + 0] = a; red[wv][k * 2 + 1] = c; }
    }
    __syncthreads();
    if (t < 2 * K) {
        out[b * (2 * K) + t] = red[0][t] + red[1][t] + red[2][t] + red[3][t];
    }
}

extern "C" void kernel_launch(void* const* d_in, const int* in_sizes, int n_in,
                              void* d_out, int out_size, void* d_ws, size_t ws_size,
                              hipStream_t stream) {
    const float* x   = (const float*)d_in[0];
    const float* sig = (const float*)d_in[1];
    const float* w1  = (const float*)d_in[2];
    const float* w2  = (const float*)d_in[3];
    const float* w3  = (const float*)d_in[4];
    const float* w4  = (const float*)d_in[5];
    const float* g1  = (const float*)d_in[6];
    const float* b1  = (const float*)d_in[7];
    const float* m1  = (const float*)d_in[8];
    const float* v1  = (const float*)d_in[9];
    const float* g2  = (const float*)d_in[10];
    const float* b2  = (const float*)d_in[11];
    const float* m2  = (const float*)d_in[12];
    const float* v2  = (const float*)d_in[13];
    const float* g3  = (const float*)d_in[14];
    const float* b3  = (const float*)d_in[15];
    const float* m3  = (const float*)d_in[16];
    const float* v3  = (const float*)d_in[17];

    char* ws = (char*)d_ws;
    size_t off = 0;
    auto alloc = [&](size_t bytes) {
        char* p = ws + off;
        off += (bytes + 255) & ~(size_t)255;
        return p;
    };
    unsigned short* h1  = (unsigned short*)alloc((size_t)B * F1 * K * C1 * 2);  // reused as h3
    unsigned short* h2  = (unsigned short*)alloc((size_t)B * F2 * K * C2 * 2);
    float* w1f = (float*)alloc((size_t)C1 * 2 * 9 * 4);
    float* t1  = (float*)alloc((size_t)C1 * 4);
    unsigned short* wp2 = (unsigned short*)alloc((size_t)9 * C1 * C2 * 2);
    float* t2  = (float*)alloc((size_t)C2 * 4);
    unsigned short* wp3 = (unsigned short*)alloc((size_t)9 * C2 * C3 * 2);
    float* t3  = (float*)alloc((size_t)C3 * 4);
    float* zbuf = (float*)alloc(16);
    unsigned short* h3 = h1;

    repack_w1<<<(C1 * 2 * 9 + 255) / 256, 256, 0, stream>>>(w1, g1, b1, m1, v1, w1f, t1, zbuf);
    repack_mfma<C1, C2><<<(9 * C1 * C2 + 255) / 256, 256, 0, stream>>>(w2, g2, b2, m2, v2, wp2, t2);
    repack_mfma<C2, C3><<<(9 * C2 * C3 + 255) / 256, 256, 0, stream>>>(w3, g3, b3, m3, v3, wp3, t3);

    conv1_kernel<<<B, 256, 0, stream>>>(x, sig, w1f, t1, h1);
    conv_mfma<C1, C2, F1, 4><<<dim3(F2 / 4, B), 256, 0, stream>>>(h1, wp2, t2, (const unsigned short*)zbuf, h2);
    conv_mfma<C2, C3, F2, 3><<<dim3(F3 / 4, B), 256, 0, stream>>>(h2, wp3, t3, (const unsigned short*)zbuf, h3);
    conv4_kernel<<<B, 256, 0, stream>>>(h3, w4, (float*)d_out);
}